// Round 13
// baseline (276.389 us; speedup 1.0000x reference)
//
#include <hip/hip_runtime.h>
#include <hip/hip_bf16.h>

// Sizes (fixed by the reference)
#define BATCH 8192
#define DIM   128
#define NPAT  64
#define VOCAB 32000
#define CHUNKS (BATCH / 16)   // 512 16-row A chunks

// GEMM geometry (R13): 500 blocks x 256 thr (4 waves). Block = (panel, split):
// panel 0..124 owns cols [panel*256, +256) via 4 waves x 64 cols; split 0..3
// sweeps chunks [split*128, +128). All 4 waves work the SAME chunk each iter
// -> each output row receives 4 x 256 B = 1-KB contiguous within one burst.
// panel-major ordering: co-resident neighbor panels write the same rows.
#define NPANEL 125
#define NSPLITS 4
#define CPB    128            // chunks per block (per split)

typedef __attribute__((ext_vector_type(8))) short short8;   // 8 bf16 = 4 VGPRs
typedef __attribute__((ext_vector_type(4))) float f32x4;    // MFMA accum

// ---------------------------------------------------------------------------
// Phase A: per-row attention/softmax/rec/self-gate, all f32, output gated bf16.
// One wave per batch row, 4 rows (4 waves) per block.  (proven, ~15 us)
// ---------------------------------------------------------------------------
__global__ __launch_bounds__(256) void phaseA_kernel(
    const float* __restrict__ x,            // [B, D]
    const float* __restrict__ attn_w,       // [D, P]
    const float* __restrict__ attn_b,       // [P]
    const float* __restrict__ pattern_dict, // [P, D]
    const float* __restrict__ self_w,       // [D, D]
    const float* __restrict__ self_b,       // [D]
    __hip_bfloat16* __restrict__ gated)     // [B, D] bf16 out
{
    __shared__ float xs[4][DIM];
    __shared__ float wls[4][NPAT];
    __shared__ float recs[4][DIM];

    const int lane = threadIdx.x & 63;
    const int wid  = threadIdx.x >> 6;
    const int row  = blockIdx.x * 4 + wid;

    xs[wid][lane]      = x[row * DIM + lane];
    xs[wid][lane + 64] = x[row * DIM + 64 + lane];
    __syncthreads();

    float acc = attn_b[lane];
#pragma unroll 8
    for (int d = 0; d < DIM; ++d)
        acc += xs[wid][d] * attn_w[d * NPAT + lane];

    float m = acc;
#pragma unroll
    for (int o = 32; o; o >>= 1) m = fmaxf(m, __shfl_xor(m, o));
    float e = expf(acc - m);
    float s = e;
#pragma unroll
    for (int o = 32; o; o >>= 1) s += __shfl_xor(s, o);
    float w = e / s;
    wls[wid][lane] = w;
    __syncthreads();

    float r0 = 0.f, r1 = 0.f;
#pragma unroll 8
    for (int p = 0; p < NPAT; ++p) {
        float wp = wls[wid][p];
        r0 += wp * pattern_dict[p * DIM + lane];
        r1 += wp * pattern_dict[p * DIM + 64 + lane];
    }
    recs[wid][lane]      = r0;
    recs[wid][lane + 64] = r1;
    __syncthreads();

    float s0 = self_b[lane], s1 = self_b[lane + 64];
#pragma unroll 8
    for (int k = 0; k < DIM; ++k) {
        float rk = recs[wid][k];
        s0 += rk * self_w[k * DIM + lane];
        s1 += rk * self_w[k * DIM + 64 + lane];
    }

    float p0 = s0 - r0, p1 = s1 - r1;
    float ss = p0 * p0 + p1 * p1;
#pragma unroll
    for (int o = 32; o; o >>= 1) ss += __shfl_xor(ss, o);
    float mag = sqrtf(ss);
    float g = 1.f / (1.f + expf(-mag));

    gated[row * DIM + lane]      = __float2bfloat16(r0 * g);
    gated[row * DIM + 64 + lane] = __float2bfloat16(r1 * g);
}

// ---------------------------------------------------------------------------
// Repack A: gated [B,D] bf16 -> Af fragment-major, 512 chunks x 4096 B.
// Af[((ch*4 + ks)*64 + lane)*8 + j] = gated[ch*16 + (lane&15)][ks*32 + (lane>>4)*8 + j]
// GEMM A-loads become contiguous 16 B/lane (1-KB wave-coalesced).
// ---------------------------------------------------------------------------
__global__ __launch_bounds__(256) void repack_a_kernel(
    const __hip_bfloat16* __restrict__ gated,
    __hip_bfloat16* __restrict__ Af)
{
    const int lane = threadIdx.x & 63;
    const int wv   = threadIdx.x >> 6;    // 0..3
    const int ch   = blockIdx.x * 4 + wv; // 0..511
    const int r16  = lane & 15;
    const int kq   = lane >> 4;
#pragma unroll
    for (int ks = 0; ks < 4; ++ks) {
        short8 v = *reinterpret_cast<const short8*>(
            gated + (size_t)(ch * 16 + r16) * DIM + ks * 32 + kq * 8);
        *reinterpret_cast<short8*>(
            Af + ((size_t)(ch * 4 + ks) * 64 + lane) * 8) = v;
    }
}

// ---------------------------------------------------------------------------
// Repack W: out_w [D=128, V] f32 -> Bf fragment-major bf16 (proven R5-R12).
// ---------------------------------------------------------------------------
__global__ __launch_bounds__(256) void repack_w_kernel(
    const float* __restrict__ out_w,        // [D, V]
    __hip_bfloat16* __restrict__ Bf)        // fragment-major [2000*4*64*8]
{
    __shared__ __hip_bfloat16 tile[64][136];

    const int t  = threadIdx.x;
    const int n0 = blockIdx.x * 64;
    const int c  = t & 63;
    const int k0 = t >> 6;

    for (int kk = 0; kk < DIM; kk += 4) {
        int k = kk + k0;
        tile[c][k] = __float2bfloat16(out_w[(size_t)k * VOCAB + n0 + c]);
    }
    __syncthreads();

    const int lane = t & 63;
    const int tl   = t >> 6;
    const int r16  = lane & 15;
    const int kq   = lane >> 4;
    const int gt   = (n0 >> 4) + tl;
#pragma unroll
    for (int ks = 0; ks < 4; ++ks) {
        uint4 v = *reinterpret_cast<const uint4*>(&tile[tl * 16 + r16][ks * 32 + kq * 8]);
        *reinterpret_cast<uint4*>(Bf + ((size_t)(gt * 4 + ks) * 64 + lane) * 8) = v;
    }
}

// ---------------------------------------------------------------------------
// GEMM (R12 body, R13 wave mapping): barrier-free, A in register ping-pong.
// Block = 4 waves on ADJACENT 64-col panels, sweeping the SAME chunk each
// iteration: the 4 waves' co-scheduled stores give every touched output row
// a 1-KB contiguous burst (R12's 8-wave/8-chunk mapping yielded only 256-B
// runs -> 4.4 TB/s; run-length is the measured write-BW lever: 64B=2.95,
// 256B=4.4, seq=6.9 TB/s). No barriers, no inter-wave deps.
// Per wave-iter: 4 L2 A-loads (prefetched), 16 MFMA (bias C-in), XOR-swizzled
// LDS pad transpose, 4 store instrs x 4 rows x 256 B.
// ---------------------------------------------------------------------------
__global__ __launch_bounds__(256, 2) void gemm_kernel(
    const __hip_bfloat16* __restrict__ Af,  // fragment-major A
    const __hip_bfloat16* __restrict__ Bf,  // fragment-major W
    const float* __restrict__ bias,         // [V]
    float* __restrict__ out)                // [B, V]
{
    __shared__ char epi[4][4096];           // per-wave private transpose pad

    const int lane  = threadIdx.x & 63;
    const int w     = threadIdx.x >> 6;     // 0..3
    const int r16   = lane & 15;
    const int kq    = lane >> 4;            // 0..3
    const int hi    = lane >> 4;
    const int lo    = lane & 15;
    const int panel = blockIdx.x % NPANEL;  // fast: neighbors co-resident
    const int split = blockIdx.x / NPANEL;  // 0..3
    const int col0  = panel * 256 + w * 64;
    const int t0    = panel * 16 + w * 4;   // first n-tile of this wave
    const int ch0   = split * CPB;

    // B fragments for this wave's 4 tiles: registers for the whole kernel.
    short8 b[4][4];
#pragma unroll
    for (int t = 0; t < 4; ++t)
#pragma unroll
        for (int ks = 0; ks < 4; ++ks)
            b[t][ks] = *reinterpret_cast<const short8*>(
                Bf + ((size_t)((t0 + t) * 4 + ks) * 64 + lane) * 8);

    // bias as MFMA C-in (D row = n = kq*4 + reg)
    f32x4 bv[4];
#pragma unroll
    for (int t = 0; t < 4; ++t)
        bv[t] = *reinterpret_cast<const f32x4*>(bias + col0 + t * 16 + kq * 4);

    char* pad = &epi[w][0];

    auto aload = [&](int ch, short8* a) {
#pragma unroll
        for (int ks = 0; ks < 4; ++ks)
            a[ks] = *reinterpret_cast<const short8*>(
                Af + ((size_t)(ch * 4 + ks) * 64 + lane) * 8);
    };

    short8 a0[4], a1[4];
    aload(ch0, a0);                          // prologue: first chunk

#pragma unroll 2
    for (int c = 0; c < CPB; ++c) {
        short8* acur = (c & 1) ? a1 : a0;
        short8* anxt = (c & 1) ? a0 : a1;
        const int ch = ch0 + c;

        if (c + 1 < CPB) aload(ch + 1, anxt); // prefetch next chunk into regs

        f32x4 acc[4];
#pragma unroll
        for (int t = 0; t < 4; ++t) {
            acc[t] = bv[t];
#pragma unroll
            for (int ks = 0; ks < 4; ++ks)
                acc[t] = __builtin_amdgcn_mfma_f32_16x16x32_bf16(
                    b[t][ks], acur[ks], acc[t], 0, 0, 0);
        }

        // ---- per-wave epilogue transpose (XOR-swizzled, bank-spread) ----
#pragma unroll
        for (int t = 0; t < 4; ++t) {
            const int pb = r16 * 256 + ((t * 64 + kq * 16) ^ ((r16 & 7) << 4));
            *reinterpret_cast<f32x4*>(pad + pb) = acc[t];
        }
        // read back full rows; 4 store instrs x 4 rows x 256-B contiguous.
        // The block's 4 waves hit the same rows at adjacent col panels within
        // one burst window -> 1-KB runs per row at DRAM.
        const size_t orow0 = (size_t)ch * 16 * VOCAB + col0;
#pragma unroll
        for (int s = 0; s < 4; ++s) {
            const int row = s * 4 + hi;
            const int pb  = row * 256 + ((lo * 16) ^ ((row & 7) << 4));
            f32x4 v = *reinterpret_cast<const f32x4*>(pad + pb);
            *reinterpret_cast<f32x4*>(out + orow0 + (size_t)row * VOCAB + lo * 4) = v;
        }
    }
}

// ---------------------------------------------------------------------------
extern "C" void kernel_launch(void* const* d_in, const int* in_sizes, int n_in,
                              void* d_out, int out_size, void* d_ws, size_t ws_size,
                              hipStream_t stream) {
    const float* x            = (const float*)d_in[0];
    const float* pattern_dict = (const float*)d_in[1];
    const float* attn_w       = (const float*)d_in[2];
    const float* attn_b       = (const float*)d_in[3];
    const float* self_w       = (const float*)d_in[4];
    const float* self_b       = (const float*)d_in[5];
    const float* out_w        = (const float*)d_in[6];
    const float* out_b        = (const float*)d_in[7];
    float* out = (float*)d_out;

    // ws: gated 2 MB | Af 2 MB | Bf 8.2 MB
    __hip_bfloat16* gated = (__hip_bfloat16*)d_ws;
    __hip_bfloat16* Af    = (__hip_bfloat16*)((char*)d_ws + (size_t)BATCH * DIM * 2);
    __hip_bfloat16* Bf    = (__hip_bfloat16*)((char*)d_ws + (size_t)2 * BATCH * DIM * 2);

    phaseA_kernel<<<BATCH / 4, 256, 0, stream>>>(
        x, attn_w, attn_b, pattern_dict, self_w, self_b, gated);
    repack_a_kernel<<<CHUNKS / 4, 256, 0, stream>>>(gated, Af);
    repack_w_kernel<<<VOCAB / 64, 256, 0, stream>>>(out_w, Bf);
    gemm_kernel<<<NPANEL * NSPLITS, 256, 0, stream>>>(Af, Bf, out_b, out);
}

// Round 14
// 244.626 us; speedup vs baseline: 1.1298x; 1.1298x over previous
//
#include <hip/hip_runtime.h>
#include <hip/hip_bf16.h>

// Sizes (fixed by the reference)
#define BATCH 8192
#define DIM   128
#define NPAT  64
#define VOCAB 32000
#define CHUNKS (BATCH / 16)   // 512 16-row A chunks

// GEMM geometry (R14): 1000 blocks x 128 thr (2 waves). Wave owns 128 cols
// (8 tiles, B-frags = 128 VGPR) and sweeps 64 chunks (split of 8). Stores go
// through an 8-KB/wave XOR-swizzled LDS pad -> each store instruction covers
// 2 rows x 512-B contiguous (4 full 128-B lines per row). Run-length curve so
// far: 64 B/instr = 2.95 TB/s, 256 B = 4.4 TB/s; this tests 512 B.
#define NPANEL  125
#define NSPLITS 8
#define CPB     (CHUNKS / NSPLITS)    // 64 chunks per wave

typedef __attribute__((ext_vector_type(8))) short short8;   // 8 bf16 = 4 VGPRs
typedef __attribute__((ext_vector_type(4))) float f32x4;    // MFMA accum

// ---------------------------------------------------------------------------
// Phase A: per-row attention/softmax/rec/self-gate, all f32, output gated bf16.
// One wave per batch row, 4 rows (4 waves) per block.  (proven, ~15 us)
// ---------------------------------------------------------------------------
__global__ __launch_bounds__(256) void phaseA_kernel(
    const float* __restrict__ x,            // [B, D]
    const float* __restrict__ attn_w,       // [D, P]
    const float* __restrict__ attn_b,       // [P]
    const float* __restrict__ pattern_dict, // [P, D]
    const float* __restrict__ self_w,       // [D, D]
    const float* __restrict__ self_b,       // [D]
    __hip_bfloat16* __restrict__ gated)     // [B, D] bf16 out
{
    __shared__ float xs[4][DIM];
    __shared__ float wls[4][NPAT];
    __shared__ float recs[4][DIM];

    const int lane = threadIdx.x & 63;
    const int wid  = threadIdx.x >> 6;
    const int row  = blockIdx.x * 4 + wid;

    xs[wid][lane]      = x[row * DIM + lane];
    xs[wid][lane + 64] = x[row * DIM + 64 + lane];
    __syncthreads();

    float acc = attn_b[lane];
#pragma unroll 8
    for (int d = 0; d < DIM; ++d)
        acc += xs[wid][d] * attn_w[d * NPAT + lane];

    float m = acc;
#pragma unroll
    for (int o = 32; o; o >>= 1) m = fmaxf(m, __shfl_xor(m, o));
    float e = expf(acc - m);
    float s = e;
#pragma unroll
    for (int o = 32; o; o >>= 1) s += __shfl_xor(s, o);
    float w = e / s;
    wls[wid][lane] = w;
    __syncthreads();

    float r0 = 0.f, r1 = 0.f;
#pragma unroll 8
    for (int p = 0; p < NPAT; ++p) {
        float wp = wls[wid][p];
        r0 += wp * pattern_dict[p * DIM + lane];
        r1 += wp * pattern_dict[p * DIM + 64 + lane];
    }
    recs[wid][lane]      = r0;
    recs[wid][lane + 64] = r1;
    __syncthreads();

    float s0 = self_b[lane], s1 = self_b[lane + 64];
#pragma unroll 8
    for (int k = 0; k < DIM; ++k) {
        float rk = recs[wid][k];
        s0 += rk * self_w[k * DIM + lane];
        s1 += rk * self_w[k * DIM + 64 + lane];
    }

    float p0 = s0 - r0, p1 = s1 - r1;
    float ss = p0 * p0 + p1 * p1;
#pragma unroll
    for (int o = 32; o; o >>= 1) ss += __shfl_xor(ss, o);
    float mag = sqrtf(ss);
    float g = 1.f / (1.f + expf(-mag));

    gated[row * DIM + lane]      = __float2bfloat16(r0 * g);
    gated[row * DIM + 64 + lane] = __float2bfloat16(r1 * g);
}

// ---------------------------------------------------------------------------
// Repack A: gated [B,D] bf16 -> Af fragment-major, 512 chunks x 4096 B.
// Af[((ch*4 + ks)*64 + lane)*8 + j] = gated[ch*16 + (lane&15)][ks*32 + (lane>>4)*8 + j]
// ---------------------------------------------------------------------------
__global__ __launch_bounds__(256) void repack_a_kernel(
    const __hip_bfloat16* __restrict__ gated,
    __hip_bfloat16* __restrict__ Af)
{
    const int lane = threadIdx.x & 63;
    const int wv   = threadIdx.x >> 6;    // 0..3
    const int ch   = blockIdx.x * 4 + wv; // 0..511
    const int r16  = lane & 15;
    const int kq   = lane >> 4;
#pragma unroll
    for (int ks = 0; ks < 4; ++ks) {
        short8 v = *reinterpret_cast<const short8*>(
            gated + (size_t)(ch * 16 + r16) * DIM + ks * 32 + kq * 8);
        *reinterpret_cast<short8*>(
            Af + ((size_t)(ch * 4 + ks) * 64 + lane) * 8) = v;
    }
}

// ---------------------------------------------------------------------------
// Repack W: out_w [D=128, V] f32 -> Bf fragment-major bf16 (proven R5-R13).
// ---------------------------------------------------------------------------
__global__ __launch_bounds__(256) void repack_w_kernel(
    const float* __restrict__ out_w,        // [D, V]
    __hip_bfloat16* __restrict__ Bf)        // fragment-major [2000*4*64*8]
{
    __shared__ __hip_bfloat16 tile[64][136];

    const int t  = threadIdx.x;
    const int n0 = blockIdx.x * 64;
    const int c  = t & 63;
    const int k0 = t >> 6;

    for (int kk = 0; kk < DIM; kk += 4) {
        int k = kk + k0;
        tile[c][k] = __float2bfloat16(out_w[(size_t)k * VOCAB + n0 + c]);
    }
    __syncthreads();

    const int lane = t & 63;
    const int tl   = t >> 6;
    const int r16  = lane & 15;
    const int kq   = lane >> 4;
    const int gt   = (n0 >> 4) + tl;
#pragma unroll
    for (int ks = 0; ks < 4; ++ks) {
        uint4 v = *reinterpret_cast<const uint4*>(&tile[tl * 16 + r16][ks * 32 + kq * 8]);
        *reinterpret_cast<uint4*>(Bf + ((size_t)(gt * 4 + ks) * 64 + lane) * 8) = v;
    }
}

// ---------------------------------------------------------------------------
// GEMM (R14): barrier-free, 128-col waves -> 512-B-per-row store runs.
// Wave owns 8 n-tiles; b[8][4] (128 VGPR) loaded once from Bf. Bias needs
// only ONE f32x4/lane (store col fixed per lane) added at epi read-back.
// A in register ping-pong from L2-resident Af (prefetched). Per iter:
// 32 MFMA, 8 swizzled pad writes, 8 store instrs x (2 rows x 512 B).
// VGPR ~216 -> 2 waves/SIMD; store-drain-bound regime tolerates low
// occupancy (fill hits 6.9 TB/s at ~3.6 waves/CU).
// ---------------------------------------------------------------------------
__global__ __launch_bounds__(128, 2) void gemm_kernel(
    const __hip_bfloat16* __restrict__ Af,  // fragment-major A
    const __hip_bfloat16* __restrict__ Bf,  // fragment-major W
    const float* __restrict__ bias,         // [V]
    float* __restrict__ out)                // [B, V]
{
    __shared__ char epi[2][8192];           // per-wave pad: 16 rows x 512 B

    const int lane  = threadIdx.x & 63;
    const int w     = threadIdx.x >> 6;     // 0..1
    const int r16   = lane & 15;
    const int kq    = lane >> 4;            // 0..3
    const int rr    = lane >> 5;            // store row parity
    const int l31   = lane & 31;            // store col slot
    const int panel = blockIdx.x % NPANEL;
    const int split = blockIdx.x / NPANEL;  // 0..7
    const int col0  = panel * 256 + w * 128;
    const int t0    = panel * 16 + w * 8;   // first of 8 n-tiles
    const int ch0   = split * CPB;

    // B fragments for this wave's 8 tiles: registers for the whole kernel.
    short8 b[8][4];
#pragma unroll
    for (int t = 0; t < 8; ++t)
#pragma unroll
        for (int ks = 0; ks < 4; ++ks)
            b[t][ks] = *reinterpret_cast<const short8*>(
                Bf + ((size_t)((t0 + t) * 4 + ks) * 64 + lane) * 8);

    // bias: each lane's store column is fixed -> one f32x4 for the kernel.
    const f32x4 bb = *reinterpret_cast<const f32x4*>(bias + col0 + l31 * 4);

    char* pad = &epi[w][0];

    auto aload = [&](int ch, short8* a) {
#pragma unroll
        for (int ks = 0; ks < 4; ++ks)
            a[ks] = *reinterpret_cast<const short8*>(
                Af + ((size_t)(ch * 4 + ks) * 64 + lane) * 8);
    };

    short8 a0[4], a1[4];
    aload(ch0, a0);                          // prologue: first chunk

#pragma unroll 2
    for (int c = 0; c < CPB; ++c) {
        short8* acur = (c & 1) ? a1 : a0;
        short8* anxt = (c & 1) ? a0 : a1;
        const int ch = ch0 + c;

        if (c + 1 < CPB) aload(ch + 1, anxt); // prefetch next chunk into regs

        f32x4 acc[8];
#pragma unroll
        for (int t = 0; t < 8; ++t) {
            f32x4 z = {};
#pragma unroll
            for (int ks = 0; ks < 4; ++ks)
                z = __builtin_amdgcn_mfma_f32_16x16x32_bf16(
                    b[t][ks], acur[ks], z, 0, 0, 0);
            acc[t] = z;
        }

        // ---- epi pad write: row r16, colbytes t*64 + kq*16, XOR-swizzled ----
#pragma unroll
        for (int t = 0; t < 8; ++t) {
            const int pb = r16 * 512 + ((t * 64 + kq * 16) ^ ((r16 & 7) << 4));
            *reinterpret_cast<f32x4*>(pad + pb) = acc[t];
        }

        // ---- stores: 8 instrs x (2 rows x 512-B contiguous runs) ----
        const size_t orow0 = (size_t)ch * 16 * VOCAB + col0;
#pragma unroll
        for (int s = 0; s < 8; ++s) {
            const int row = 2 * s + rr;
            const int pb  = row * 512 + ((l31 * 16) ^ ((row & 7) << 4));
            f32x4 v = *reinterpret_cast<const f32x4*>(pad + pb);
            v += bb;
            *reinterpret_cast<f32x4*>(out + orow0 + (size_t)row * VOCAB + l31 * 4) = v;
        }
    }
}

// ---------------------------------------------------------------------------
extern "C" void kernel_launch(void* const* d_in, const int* in_sizes, int n_in,
                              void* d_out, int out_size, void* d_ws, size_t ws_size,
                              hipStream_t stream) {
    const float* x            = (const float*)d_in[0];
    const float* pattern_dict = (const float*)d_in[1];
    const float* attn_w       = (const float*)d_in[2];
    const float* attn_b       = (const float*)d_in[3];
    const float* self_w       = (const float*)d_in[4];
    const float* self_b       = (const float*)d_in[5];
    const float* out_w        = (const float*)d_in[6];
    const float* out_b        = (const float*)d_in[7];
    float* out = (float*)d_out;

    // ws: gated 2 MB | Af 2 MB | Bf 8.2 MB
    __hip_bfloat16* gated = (__hip_bfloat16*)d_ws;
    __hip_bfloat16* Af    = (__hip_bfloat16*)((char*)d_ws + (size_t)BATCH * DIM * 2);
    __hip_bfloat16* Bf    = (__hip_bfloat16*)((char*)d_ws + (size_t)2 * BATCH * DIM * 2);

    phaseA_kernel<<<BATCH / 4, 256, 0, stream>>>(
        x, attn_w, attn_b, pattern_dict, self_w, self_b, gated);
    repack_a_kernel<<<CHUNKS / 4, 256, 0, stream>>>(gated, Af);
    repack_w_kernel<<<VOCAB / 64, 256, 0, stream>>>(out_w, Bf);
    gemm_kernel<<<NPANEL * NSPLITS, 128, 0, stream>>>(Af, Bf, out_b, out);
}